// Round 2
// baseline (182.121 us; speedup 1.0000x reference)
//
#include <hip/hip_runtime.h>
#include <hip/hip_bf16.h>

// Shapes (fixed by the problem): B=2048, S=50, D=128, H=8, L=128, HL=1024.
// Strategy: fp16 MFMA everywhere (4x lower rounding error than bf16, same
// MFMA rate), fp32 accumulation/softmax. Weights are pre-scaled by -log2(e)
// so sigmoid(z) = rcp(1 + exp2(acc)) directly.

typedef _Float16 f16x8 __attribute__((ext_vector_type(8)));
typedef float f32x4 __attribute__((ext_vector_type(4)));

#define LOG2E 1.44269504088896340736f

__device__ __forceinline__ unsigned short f2h(float f) {
  _Float16 h = (_Float16)f;                       // v_cvt_f16_f32, RTNE
  return __builtin_bit_cast(unsigned short, h);
}
__device__ __forceinline__ float h2f(unsigned short s) {
  return (float)__builtin_bit_cast(_Float16, s);
}
__device__ __forceinline__ float fexp2(float x) {
#if __has_builtin(__builtin_amdgcn_exp2f)
  return __builtin_amdgcn_exp2f(x);
#else
  return exp2f(x);
#endif
}
__device__ __forceinline__ float frcp(float x) {
#if __has_builtin(__builtin_amdgcn_rcpf)
  return __builtin_amdgcn_rcpf(x);
#else
  return 1.0f / x;
#endif
}
// sigmoid(z) given acc = -log2(e)*z (weights pre-scaled)
__device__ __forceinline__ float sig_scaled(float a) {
  return frcp(1.0f + fexp2(a));
}

// ---------------------------------------------------------------------------
// prep: WqT/WkT/WvT [n=h*128+l][d] and OT [d][hl], all fp16, scaled by -log2e
// ws16 layout (elements): [0]WqT [131072]WkT [262144]WvT [393216]OT
// ---------------------------------------------------------------------------
__global__ void prep_kernel(const float* __restrict__ Wq, const float* __restrict__ Wk,
                            const float* __restrict__ Wv, const float* __restrict__ O,
                            unsigned short* __restrict__ ws16) {
  const float NS = -LOG2E;
  int tid = blockIdx.x * 256 + threadIdx.x;
  for (int j = tid; j < 4 * 131072; j += 512 * 256) {
    int which = j >> 17;
    int i = j & 131071;
    float val;
    if (which < 3) {
      const float* W = (which == 0) ? Wq : ((which == 1) ? Wk : Wv);
      int n = i >> 7, d = i & 127;
      int h = n >> 7, lidx = n & 127;
      val = W[h * 16384 + d * 128 + lidx];
    } else {
      int n = i >> 10, k = i & 1023;   // n = output col d, k = hl
      val = O[k * 128 + n];
    }
    ws16[j] = f2h(val * NS);
  }
}

// ---------------------------------------------------------------------------
// kw_all[b][n] = sigmoid(origin_b . Wk[:,n]) * Ws_flat[n]   (fp16)
// grid (32, 4): 64 batches x 256 n per block, 4 waves x 64 n
// ---------------------------------------------------------------------------
__global__ __launch_bounds__(256, 2) void kw_kernel(
    const float* __restrict__ x, const float* __restrict__ Ws,
    const unsigned short* __restrict__ WkT, unsigned short* __restrict__ kw_all) {
  __shared__ __align__(16) char lds[16384];
  const int tid = threadIdx.x;
  const int b0 = blockIdx.x * 64;
  for (int i = tid; i < 2048; i += 256) {
    int row = i >> 5, c4 = i & 31;
    const float4 v = *(const float4*)(x + (size_t)(b0 + row) * 6400 + c4 * 4);
    uint2 pk;
    pk.x = (unsigned)f2h(v.x) | ((unsigned)f2h(v.y) << 16);
    pk.y = (unsigned)f2h(v.z) | ((unsigned)f2h(v.w) << 16);
    *(uint2*)(lds + row * 256 + ((c4 * 8) ^ ((row & 7) << 4))) = pk;
  }
  __syncthreads();
  const int w = tid >> 6, l = tid & 63, l15 = l & 15, l4 = l >> 4;
  f16x8 af[4][4];
#pragma unroll
  for (int mt = 0; mt < 4; ++mt)
#pragma unroll
    for (int kt = 0; kt < 4; ++kt) {
      int row = mt * 16 + l15;
      int c = kt * 64 + l4 * 16;
      af[mt][kt] = *(const f16x8*)(lds + row * 256 + (c ^ ((row & 7) << 4)));
    }
  const f16x8* B8 = (const f16x8*)WkT;
  for (int nt = 0; nt < 4; ++nt) {
    const int n0 = blockIdx.y * 256 + w * 64 + nt * 16;
    f16x8 bfr[4];
#pragma unroll
    for (int kt = 0; kt < 4; ++kt) bfr[kt] = B8[(size_t)(n0 + l15) * 16 + kt * 4 + l4];
    f32x4 acc[4];
#pragma unroll
    for (int mt = 0; mt < 4; ++mt) acc[mt] = (f32x4){0.f, 0.f, 0.f, 0.f};
#pragma unroll
    for (int mt = 0; mt < 4; ++mt)
#pragma unroll
      for (int kt = 0; kt < 4; ++kt)
        acc[mt] = __builtin_amdgcn_mfma_f32_16x16x32_f16(af[mt][kt], bfr[kt], acc[mt], 0, 0, 0);
    const float wsv = Ws[n0 + l15];
#pragma unroll
    for (int mt = 0; mt < 4; ++mt)
#pragma unroll
      for (int r = 0; r < 4; ++r) {
        int row = b0 + mt * 16 + l4 * 4 + r;
        kw_all[(size_t)row * 1024 + n0 + l15] = f2h(sig_scaled(acc[mt][r]) * wsv);
      }
  }
}

// ---------------------------------------------------------------------------
// fused: per batch: q = sig(x.Wq) -> score -> softmax -> v = sig(x.Wv) -> res
// 1 block per batch, 4 waves, each wave owns n in [256w, 256w+256) (2 heads)
// ---------------------------------------------------------------------------
__global__ __launch_bounds__(256, 3) void fused_kernel(
    const float* __restrict__ x,
    const unsigned short* __restrict__ WqT, const unsigned short* __restrict__ WvT,
    const unsigned short* __restrict__ kw_all, unsigned short* __restrict__ res_all) {
  __shared__ __align__(16) char xlds[16384];
  __shared__ float kw_lds[1024];
  __shared__ float score_lds[64][8];
  __shared__ float attn_lds[64][8];
  const int tid = threadIdx.x;
  const int b = blockIdx.x;
  const float* xb = x + (size_t)b * 6400;
  for (int i = tid; i < 2048; i += 256) {
    int row = i >> 5, c4 = i & 31;
    uint2 pk = {0u, 0u};
    if (row < 50) {
      const float4 v = *(const float4*)(xb + row * 128 + c4 * 4);
      pk.x = (unsigned)f2h(v.x) | ((unsigned)f2h(v.y) << 16);
      pk.y = (unsigned)f2h(v.z) | ((unsigned)f2h(v.w) << 16);
    }
    *(uint2*)(xlds + row * 256 + ((c4 * 8) ^ ((row & 7) << 4))) = pk;
  }
  const unsigned short* kwb = kw_all + (size_t)b * 1024;
  for (int i = tid; i < 1024; i += 256) kw_lds[i] = h2f(kwb[i]);
  __syncthreads();

  const int w = tid >> 6, l = tid & 63, l15 = l & 15, l4 = l >> 4;
  f16x8 af[4][4];
#pragma unroll
  for (int mt = 0; mt < 4; ++mt)
#pragma unroll
    for (int kt = 0; kt < 4; ++kt) {
      int row = mt * 16 + l15;
      int c = kt * 64 + l4 * 16;
      af[mt][kt] = *(const f16x8*)(xlds + row * 256 + (c ^ ((row & 7) << 4)));
    }

  // ---- Q pass: accumulate score ----
  const f16x8* Bq = (const f16x8*)WqT;
  float sAcc[4][4];
#pragma unroll
  for (int mt = 0; mt < 4; ++mt)
#pragma unroll
    for (int r = 0; r < 4; ++r) sAcc[mt][r] = 0.f;
  f16x8 bcur[4], bnext[4];
  {
    const size_t nn = (size_t)(w * 256 + l15);
#pragma unroll
    for (int kt = 0; kt < 4; ++kt) bcur[kt] = Bq[nn * 16 + kt * 4 + l4];
  }
  for (int nt = 0; nt < 16; ++nt) {
    if (nt < 15) {
      const size_t nn = (size_t)(w * 256 + (nt + 1) * 16 + l15);
#pragma unroll
      for (int kt = 0; kt < 4; ++kt) bnext[kt] = Bq[nn * 16 + kt * 4 + l4];
    }
    f32x4 acc[4];
#pragma unroll
    for (int mt = 0; mt < 4; ++mt) acc[mt] = (f32x4){0.f, 0.f, 0.f, 0.f};
#pragma unroll
    for (int mt = 0; mt < 4; ++mt)
#pragma unroll
      for (int kt = 0; kt < 4; ++kt)
        acc[mt] = __builtin_amdgcn_mfma_f32_16x16x32_f16(af[mt][kt], bcur[kt], acc[mt], 0, 0, 0);
    const int n0 = w * 256 + nt * 16;
    const float kwv = kw_lds[n0 + l15];
#pragma unroll
    for (int mt = 0; mt < 4; ++mt)
#pragma unroll
      for (int r = 0; r < 4; ++r)
        sAcc[mt][r] = fmaf(sig_scaled(acc[mt][r]), kwv, sAcc[mt][r]);
    if ((nt & 7) == 7) {
      const int h = n0 >> 7;
#pragma unroll
      for (int mt = 0; mt < 4; ++mt)
#pragma unroll
        for (int r = 0; r < 4; ++r) {
          float v = sAcc[mt][r];
          v += __shfl_xor(v, 1);
          v += __shfl_xor(v, 2);
          v += __shfl_xor(v, 4);
          v += __shfl_xor(v, 8);
          if (l15 == 0) score_lds[mt * 16 + l4 * 4 + r][h] = v;
          sAcc[mt][r] = 0.f;
        }
    }
#pragma unroll
    for (int kt = 0; kt < 4; ++kt) bcur[kt] = bnext[kt];
  }
  __syncthreads();

  // ---- softmax over s (wave 0; lanes = s, rows >= 50 masked) ----
  if (w == 0) {
    for (int h = 0; h < 8; ++h) {
      float s = (l < 50) ? score_lds[l][h] : -3.0e38f;
      float m = s;
#pragma unroll
      for (int d = 1; d < 64; d <<= 1) m = fmaxf(m, __shfl_xor(m, d));
      float e = (l < 50) ? fexp2((s - m) * LOG2E) : 0.f;
      float t = e;
#pragma unroll
      for (int d = 1; d < 64; d <<= 1) t += __shfl_xor(t, d);
      attn_lds[l][h] = e * frcp(t);
    }
  }
  __syncthreads();

  // ---- V pass: res[n] = sum_s attn[s,h] * sigmoid(v) ----
  const f16x8* Bv = (const f16x8*)WvT;
  float at[4][4];
  {
    const size_t nn = (size_t)(w * 256 + l15);
#pragma unroll
    for (int kt = 0; kt < 4; ++kt) bcur[kt] = Bv[nn * 16 + kt * 4 + l4];
  }
  for (int nt = 0; nt < 16; ++nt) {
    if (nt < 15) {
      const size_t nn = (size_t)(w * 256 + (nt + 1) * 16 + l15);
#pragma unroll
      for (int kt = 0; kt < 4; ++kt) bnext[kt] = Bv[nn * 16 + kt * 4 + l4];
    }
    const int n0 = w * 256 + nt * 16;
    if ((nt & 7) == 0) {
      const int h = n0 >> 7;
#pragma unroll
      for (int mt = 0; mt < 4; ++mt)
#pragma unroll
        for (int r = 0; r < 4; ++r) at[mt][r] = attn_lds[mt * 16 + l4 * 4 + r][h];
    }
    f32x4 acc[4];
#pragma unroll
    for (int mt = 0; mt < 4; ++mt) acc[mt] = (f32x4){0.f, 0.f, 0.f, 0.f};
#pragma unroll
    for (int mt = 0; mt < 4; ++mt)
#pragma unroll
      for (int kt = 0; kt < 4; ++kt)
        acc[mt] = __builtin_amdgcn_mfma_f32_16x16x32_f16(af[mt][kt], bcur[kt], acc[mt], 0, 0, 0);
    float part = 0.f;
#pragma unroll
    for (int mt = 0; mt < 4; ++mt)
#pragma unroll
      for (int r = 0; r < 4; ++r)
        part = fmaf(at[mt][r], sig_scaled(acc[mt][r]), part);
    part += __shfl_xor(part, 16);
    part += __shfl_xor(part, 32);
    if (l < 16) res_all[(size_t)b * 1024 + n0 + l] = f2h(part);
#pragma unroll
    for (int kt = 0; kt < 4; ++kt) bcur[kt] = bnext[kt];
  }
}

// ---------------------------------------------------------------------------
// out[b][d] = sigmoid(res[b,:] . O[:,d]) + x[b][0][d]
// 128 blocks x 16 rows; 4 waves x 32 cols; K = 1024
// ---------------------------------------------------------------------------
__global__ __launch_bounds__(256, 4) void out_kernel(
    const unsigned short* __restrict__ res_all, const unsigned short* __restrict__ OT,
    const float* __restrict__ x, float* __restrict__ out) {
  const int tid = threadIdx.x;
  const int w = tid >> 6, l = tid & 63, l15 = l & 15, l4 = l >> 4;
  const int b0 = blockIdx.x * 16;
  const f16x8* A8 = (const f16x8*)res_all;
  const f16x8* B8 = (const f16x8*)OT;
  f32x4 acc0 = (f32x4){0.f, 0.f, 0.f, 0.f};
  f32x4 acc1 = (f32x4){0.f, 0.f, 0.f, 0.f};
  const int n0 = w * 32;
#pragma unroll 4
  for (int kt = 0; kt < 32; ++kt) {
    f16x8 a = A8[(size_t)(b0 + l15) * 128 + kt * 4 + l4];
    f16x8 bq0 = B8[(size_t)(n0 + l15) * 128 + kt * 4 + l4];
    f16x8 bq1 = B8[(size_t)(n0 + 16 + l15) * 128 + kt * 4 + l4];
    acc0 = __builtin_amdgcn_mfma_f32_16x16x32_f16(a, bq0, acc0, 0, 0, 0);
    acc1 = __builtin_amdgcn_mfma_f32_16x16x32_f16(a, bq1, acc1, 0, 0, 0);
  }
#pragma unroll
  for (int r = 0; r < 4; ++r) {
    int row = b0 + l4 * 4 + r;
    int col0 = n0 + l15;
    int col1 = n0 + 16 + l15;
    out[(size_t)row * 128 + col0] = sig_scaled(acc0[r]) + x[(size_t)row * 6400 + col0];
    out[(size_t)row * 128 + col1] = sig_scaled(acc1[r]) + x[(size_t)row * 6400 + col1];
  }
}

extern "C" void kernel_launch(void* const* d_in, const int* in_sizes, int n_in,
                              void* d_out, int out_size, void* d_ws, size_t ws_size,
                              hipStream_t stream) {
  const float* x  = (const float*)d_in[0];
  const float* Wq = (const float*)d_in[1];
  const float* Wk = (const float*)d_in[2];
  const float* Wv = (const float*)d_in[3];
  const float* Ws = (const float*)d_in[4];
  const float* O  = (const float*)d_in[5];
  float* out = (float*)d_out;

  unsigned short* ws16    = (unsigned short*)d_ws;
  unsigned short* WqT     = ws16;                    // 131072 elems
  unsigned short* WkT     = ws16 + 131072;
  unsigned short* WvT     = ws16 + 262144;
  unsigned short* OT      = ws16 + 393216;
  unsigned short* kw_all  = ws16 + 524288;           // 2048*1024 fp16
  unsigned short* res_all = ws16 + 524288 + 2097152; // 2048*1024 fp16

  prep_kernel<<<512, 256, 0, stream>>>(Wq, Wk, Wv, O, ws16);
  kw_kernel<<<dim3(32, 4), 256, 0, stream>>>(x, Ws, WkT, kw_all);
  fused_kernel<<<2048, 256, 0, stream>>>(x, WqT, WvT, kw_all, res_all);
  out_kernel<<<128, 256, 0, stream>>>(res_all, OT, x, out);
}